// Round 4
// baseline (182.224 us; speedup 1.0000x reference)
//
#include <hip/hip_runtime.h>

// Warp (flow-shifted bilinear grid sample), channels_last.
// img: [B,H,W,C] f32, flo: [B,H,W,2] f32 -> out: [B,H,W,C] f32
// B=8 H=384 W=512 C=64

constexpr int B = 8, H = 384, W = 512, C = 64;

typedef float f4 __attribute__((ext_vector_type(4)));
typedef float f2 __attribute__((ext_vector_type(2)));

// 8 threads per pixel, 2 pixels per thread (x and x+32): 16 independent img
// loads in flight per thread to hide gather latency (R3 was neutral on
// locality changes -> latency-bound, not BW-bound). Every img load remains
// 128B-contiguous per 8-lane group; stores nontemporal (write stream must
// not evict img tap lines). grid.x = W/64 = 8 -> XCD = blockIdx.x: each XCD
// owns one contiguous 64-px column band (+flow halo ~3MB < 4MB L2).
__global__ __launch_bounds__(256) void warp_bilinear_kernel(
    const float* __restrict__ img,
    const float* __restrict__ flo,
    float* __restrict__ out)
{
    int lane = threadIdx.x & 7;          // channel group
    int pix  = threadIdx.x >> 3;         // 0..31
    int y_i  = blockIdx.y;
    int b    = blockIdx.z;

    const float* imgb = img + (size_t)b * (H * W * C);
    const float* flob = flo + (size_t)b * (H * W * 2);
    float*       outb = out + (size_t)b * (H * W * C);
    unsigned co = (unsigned)(lane << 2);

    int x_base = blockIdx.x * 64 + pix;
    unsigned rowp = (unsigned)y_i * W;

    // ---- phase 1: addresses + issue all loads (2 pixels interleaved) ----
    unsigned ta[2], tb[2], tc[2], td[2], pin[2];
    float wxv[2], wyv[2];
#pragma unroll
    for (int j = 0; j < 2; ++j) {
        int x_i = x_base + j * 32;
        pin[j] = rowp + (unsigned)x_i;
        f2 f = __builtin_nontemporal_load(reinterpret_cast<const f2*>(flob + pin[j] * 2u));
        float x = (float)x_i + f.x;
        float y = (float)y_i + f.y;
        float x0f = floorf(x);
        float y0f = floorf(y);
        wxv[j] = x - x0f;
        wyv[j] = y - y0f;
        int x0 = min(max((int)x0f, 0), W - 1);
        int x1 = min(max((int)x0f + 1, 0), W - 1);
        int y0 = min(max((int)y0f, 0), H - 1);
        int y1 = min(max((int)y0f + 1, 0), H - 1);
        ta[j] = ((unsigned)y0 * W + (unsigned)x0) * C + co;
        tb[j] = ((unsigned)y1 * W + (unsigned)x0) * C + co;
        tc[j] = ((unsigned)y0 * W + (unsigned)x1) * C + co;
        td[j] = ((unsigned)y1 * W + (unsigned)x1) * C + co;
    }

    f4 Ia0[2], Ia1[2], Ib0[2], Ib1[2], Ic0[2], Ic1[2], Id0[2], Id1[2];
#pragma unroll
    for (int j = 0; j < 2; ++j) {
        Ia0[j] = *reinterpret_cast<const f4*>(imgb + ta[j]);
        Ia1[j] = *reinterpret_cast<const f4*>(imgb + ta[j] + 32u);
        Ib0[j] = *reinterpret_cast<const f4*>(imgb + tb[j]);
        Ib1[j] = *reinterpret_cast<const f4*>(imgb + tb[j] + 32u);
        Ic0[j] = *reinterpret_cast<const f4*>(imgb + tc[j]);
        Ic1[j] = *reinterpret_cast<const f4*>(imgb + tc[j] + 32u);
        Id0[j] = *reinterpret_cast<const f4*>(imgb + td[j]);
        Id1[j] = *reinterpret_cast<const f4*>(imgb + td[j] + 32u);
    }

    // ---- phase 2: blend + store ----
#pragma unroll
    for (int j = 0; j < 2; ++j) {
        float wx = wxv[j], wy = wyv[j];
        float wa = (1.0f - wx) * (1.0f - wy);
        float wb = (1.0f - wx) * wy;
        float wc = wx * (1.0f - wy);
        float wd = wx * wy;
        f4 r0 = wa * Ia0[j] + wb * Ib0[j] + wc * Ic0[j] + wd * Id0[j];
        f4 r1 = wa * Ia1[j] + wb * Ib1[j] + wc * Ic1[j] + wd * Id1[j];
        float* op = outb + pin[j] * C + co;
        __builtin_nontemporal_store(r0, reinterpret_cast<f4*>(op));
        __builtin_nontemporal_store(r1, reinterpret_cast<f4*>(op + 32));
    }
}

extern "C" void kernel_launch(void* const* d_in, const int* in_sizes, int n_in,
                              void* d_out, int out_size, void* d_ws, size_t ws_size,
                              hipStream_t stream) {
    const float* img = (const float*)d_in[0];
    const float* flo = (const float*)d_in[1];
    float* out = (float*)d_out;

    dim3 grid(W / 64, H, B);   // 8 x 384 x 8 = 24576 blocks, 64 pixels/block
    dim3 block(256);
    warp_bilinear_kernel<<<grid, block, 0, stream>>>(img, flo, out);
}